// Round 7
// baseline (1846.680 us; speedup 1.0000x reference)
//
#include <hip/hip_runtime.h>

#define NN 50000
#define EE 800000

typedef unsigned short u16;
typedef __attribute__((ext_vector_type(8))) short bf16x8;
typedef __attribute__((ext_vector_type(4))) float f32x4;

#define MFMA16(a, b, c) __builtin_amdgcn_mfma_f32_16x16x32_bf16(a, b, c, 0, 0, 0)

__device__ __forceinline__ float bf2f(u16 v) {
    union { unsigned u; float f; } x; x.u = ((unsigned)v) << 16; return x.f;
}
__device__ __forceinline__ u16 f2bf(float f) {
    union { float f; unsigned u; } x; x.f = f;
    unsigned r = x.u + 0x7FFFu + ((x.u >> 16) & 1u);
    return (u16)(r >> 16);
}

// ---------------- generic weight packing (fragment-major bf16) ----------------
// dst[kk][nf][lane][t]: k = kk*32 + (lane>>4)*8 + t (zero-padded past K), n = nf*16 + (lane&15)
__global__ void pack_frag(const float* __restrict__ W, u16* __restrict__ dst, int K, int N) {
    int i = blockIdx.x * 256 + threadIdx.x;
    int nfc = N / 16, kkc = (K + 31) / 32;
    int total = kkc * nfc * 512;
    if (i >= total) return;
    int t = i & 7, lane = (i >> 3) & 63;
    int rest = i >> 9;
    int nf = rest % nfc, kk = rest / nfc;
    int k = kk * 32 + (lane >> 4) * 8 + t, n = nf * 16 + (lane & 15);
    dst[i] = (k < K) ? f2bf(W[k * N + n]) : (u16)0;
}

// ---------------- MFMA node embedding ----------------
__global__ __launch_bounds__(256) void embed_mfma_node(
    const float* __restrict__ x, const u16* __restrict__ pW1, const float* __restrict__ b1,
    const u16* __restrict__ pW2, const float* __restrict__ b2, u16* __restrict__ out)
{
    __shared__ alignas(16) u16 A[64 * 136];
    __shared__ alignas(16) u16 Hs[64 * 72];
    int tid = threadIdx.x;
    size_t row0 = (size_t)blockIdx.x * 64;
    #pragma unroll
    for (int it = 0; it < 8; ++it) {
        int u = it * 256 + tid;
        int row = u >> 5, seg = u & 31;
        float4 v = (row0 + row < NN) ? *(const float4*)(x + (row0 + row) * 128 + seg * 4)
                                     : make_float4(0.f, 0.f, 0.f, 0.f);
        ushort4 o; o.x = f2bf(v.x); o.y = f2bf(v.y); o.z = f2bf(v.z); o.w = f2bf(v.w);
        *(ushort4*)(A + row * 136 + seg * 4) = o;
    }
    __syncthreads();
    int wave = tid >> 6, lane = tid & 63, l15 = lane & 15, l4 = lane >> 4;
    int col = wave * 16 + l15;
    f32x4 acc[4] = {};
    #pragma unroll
    for (int kk = 0; kk < 4; ++kk) {
        bf16x8 b = *(const bf16x8*)(pW1 + (size_t)((kk * 4 + wave) * 64 + lane) * 8);
        #pragma unroll
        for (int mi = 0; mi < 4; ++mi) {
            bf16x8 a = *(const bf16x8*)(A + (mi * 16 + l15) * 136 + kk * 32 + l4 * 8);
            acc[mi] = MFMA16(a, b, acc[mi]);
        }
    }
    float bias = b1[col];
    #pragma unroll
    for (int mi = 0; mi < 4; ++mi)
        #pragma unroll
        for (int r = 0; r < 4; ++r) {
            float v = acc[mi][r] + bias;
            Hs[(mi * 16 + l4 * 4 + r) * 72 + col] = f2bf(v > 0.f ? v : 0.f);
        }
    __syncthreads();
    f32x4 acc2[4] = {};
    #pragma unroll
    for (int kk = 0; kk < 2; ++kk) {
        bf16x8 b = *(const bf16x8*)(pW2 + (size_t)((kk * 4 + wave) * 64 + lane) * 8);
        #pragma unroll
        for (int mi = 0; mi < 4; ++mi) {
            bf16x8 a = *(const bf16x8*)(Hs + (mi * 16 + l15) * 72 + kk * 32 + l4 * 8);
            acc2[mi] = MFMA16(a, b, acc2[mi]);
        }
    }
    float bias2 = b2[col];
    __syncthreads();
    #pragma unroll
    for (int mi = 0; mi < 4; ++mi)
        #pragma unroll
        for (int r = 0; r < 4; ++r)
            Hs[(mi * 16 + l4 * 4 + r) * 72 + col] = f2bf(acc2[mi][r] + bias2);
    __syncthreads();
    #pragma unroll
    for (int it = 0; it < 4; ++it) {
        int u = it * 256 + tid;
        int row = u >> 4, c4 = (u & 15) * 4;
        if (row0 + row < NN) {
            ushort4 o = *(const ushort4*)(Hs + row * 72 + c4);
            *(ushort4*)(out + (row0 + row) * 64 + c4) = o;
        }
    }
}

// ---------------- MFMA edge embedding (gathers ea rows by eids -> writes PERMUTED ef0) ----------------
__global__ __launch_bounds__(256) void embed_mfma_edge(
    const float* __restrict__ ea, const int* __restrict__ eids,
    const u16* __restrict__ pW1, const float* __restrict__ b1,
    const u16* __restrict__ pW2, const float* __restrict__ b2, u16* __restrict__ out)
{
    __shared__ alignas(16) u16 A[64 * 40];
    __shared__ alignas(16) u16 Hs[64 * 72];
    __shared__ int eid_s[64];
    int tid = threadIdx.x;
    size_t row0 = (size_t)blockIdx.x * 64;
    if (tid < 64) eid_s[tid] = eids[row0 + tid];
    __syncthreads();
    #pragma unroll
    for (int it = 0; it < 8; ++it) {
        int u = it * 256 + tid;
        int row = u >> 5, k = u & 31;
        float v = (k < 19) ? ea[(size_t)eid_s[row] * 19 + k] : 0.f;
        A[row * 40 + k] = f2bf(v);
    }
    __syncthreads();
    int wave = tid >> 6, lane = tid & 63, l15 = lane & 15, l4 = lane >> 4;
    int col = wave * 16 + l15;
    f32x4 acc[4] = {};
    {
        bf16x8 b = *(const bf16x8*)(pW1 + (size_t)(wave * 64 + lane) * 8);
        #pragma unroll
        for (int mi = 0; mi < 4; ++mi) {
            bf16x8 a = *(const bf16x8*)(A + (mi * 16 + l15) * 40 + l4 * 8);
            acc[mi] = MFMA16(a, b, acc[mi]);
        }
    }
    float bias = b1[col];
    #pragma unroll
    for (int mi = 0; mi < 4; ++mi)
        #pragma unroll
        for (int r = 0; r < 4; ++r) {
            float v = acc[mi][r] + bias;
            Hs[(mi * 16 + l4 * 4 + r) * 72 + col] = f2bf(v > 0.f ? v : 0.f);
        }
    __syncthreads();
    f32x4 acc2[4] = {};
    #pragma unroll
    for (int kk = 0; kk < 2; ++kk) {
        bf16x8 b = *(const bf16x8*)(pW2 + (size_t)((kk * 4 + wave) * 64 + lane) * 8);
        #pragma unroll
        for (int mi = 0; mi < 4; ++mi) {
            bf16x8 a = *(const bf16x8*)(Hs + (mi * 16 + l15) * 72 + kk * 32 + l4 * 8);
            acc2[mi] = MFMA16(a, b, acc2[mi]);
        }
    }
    float bias2 = b2[col];
    __syncthreads();
    #pragma unroll
    for (int mi = 0; mi < 4; ++mi)
        #pragma unroll
        for (int r = 0; r < 4; ++r)
            Hs[(mi * 16 + l4 * 4 + r) * 72 + col] = f2bf(acc2[mi][r] + bias2);
    __syncthreads();
    #pragma unroll
    for (int it = 0; it < 4; ++it) {
        int u = it * 256 + tid;
        int row = u >> 4, c4 = (u & 15) * 4;
        ushort4 o = *(const ushort4*)(Hs + row * 72 + c4);
        *(ushort4*)(out + (row0 + row) * 64 + c4) = o;
    }
}

// ---------------- CSR build ----------------
__global__ void zero_cnt(int* __restrict__ cnt) {
    int i = blockIdx.x * 256 + threadIdx.x;
    if (i < NN) cnt[i] = 0;
}
__global__ void count_deg(const int* __restrict__ eidx, int* __restrict__ cnt) {
    int e = blockIdx.x * 256 + threadIdx.x;
    if (e < EE) atomicAdd(&cnt[eidx[EE + e]], 1);
}
__global__ void scan_k(const int* __restrict__ cnt, int* __restrict__ starts) {
    __shared__ int part[1024];
    int t = threadIdx.x;
    const int chunk = (NN + 1023) / 1024;
    int lo = t * chunk, hi = lo + chunk; if (hi > NN) hi = NN;
    if (lo > NN) lo = NN;
    int s = 0;
    for (int i = lo; i < hi; ++i) s += cnt[i];
    part[t] = s;
    __syncthreads();
    for (int off = 1; off < 1024; off <<= 1) {
        int v = part[t];
        int add = (t >= off) ? part[t - off] : 0;
        __syncthreads();
        part[t] = v + add;
        __syncthreads();
    }
    int run = (t == 0) ? 0 : part[t - 1];
    for (int i = lo; i < hi; ++i) { starts[i] = run; run += cnt[i]; }
    if (t == 1023) starts[NN] = EE;
}
__global__ void init_cur(const int* __restrict__ starts, int* __restrict__ cur) {
    int i = blockIdx.x * 256 + threadIdx.x;
    if (i < NN) cur[i] = starts[i];
}
__global__ void scatter_e(const int* __restrict__ eidx, int* __restrict__ cur,
                          int* __restrict__ eids) {
    int e = blockIdx.x * 256 + threadIdx.x;
    if (e < EE) {
        int pos = atomicAdd(&cur[eidx[EE + e]], 1);
        eids[pos] = e;
    }
}
__global__ void build_perm(const int* __restrict__ eidx, const int* __restrict__ eids,
                           int* __restrict__ psrc, int* __restrict__ pdst) {
    int j = blockIdx.x * 256 + threadIdx.x;
    if (j < EE) {
        int e = eids[j];
        psrc[j] = eidx[e];
        pdst[j] = eidx[EE + e];
    }
}

// ---------------- fused edge MLP v9: M-split, zero barriers, direct A-gathers ----------------
// Each wave owns 16 EDGES x all 128 hidden cols (not 32 cols x 64 edges). A-fragments are
// wave-private -> loaded directly global->VGPR (no LDS staging, no redundancy, no barriers).
// B-fragments load per-kk (L1-shared across waves). GEMM1->GEMM2 relayout + output staging go
// through a wave-private 4.2KB LDS scratch with lgkmcnt-only ordering. Numerics bit-identical
// to the verified v6 kernel (same kk chain order, same bf16 hid rounding, same f32 epilogue).
__global__ __launch_bounds__(256, 4) void edge_mlp(
    const int* __restrict__ psrc, const int* __restrict__ pdst,
    const u16* __restrict__ nf0, const u16* __restrict__ nfc,
    const u16* __restrict__ ef0, const u16* __restrict__ efc,
    const u16* __restrict__ pW1, const u16* __restrict__ pW2,
    const float* __restrict__ eb1, const float* __restrict__ eb2,
    u16* __restrict__ efn)
{
    __shared__ alignas(16) u16 X[4][16 * 132];   // wave-private scratch (stride 132 -> conflict-free A-frag reads)
    const int tid = threadIdx.x;
    const int tile0 = blockIdx.x * 64;
    const int wave = tid >> 6, lane = tid & 63;
    const int l15 = lane & 15, l4 = lane >> 4;
    const int m0 = wave * 16;
    const int rI = tile0 + m0 + l15;          // this lane's edge row (A-fragment row)
    const int koff = l4 * 8;

    const int rs = psrc[rI] * 64;
    const int rd = pdst[rI] * 64;
    const int re = rI * 64;

    // ---- GEMM1: [16 x 384] @ [384 x 128] per wave; A direct from global ----
    f32x4 acc[8] = {};
    #pragma unroll
    for (int c = 0; c < 6; ++c) {
        const u16* rp;
        if (c == 0)      rp = nf0 + rs;
        else if (c == 1) rp = nfc + rs;
        else if (c == 2) rp = nf0 + rd;
        else if (c == 3) rp = nfc + rd;
        else if (c == 4) rp = ef0 + re;
        else             rp = efc + re;
        #pragma unroll
        for (int kkl = 0; kkl < 2; ++kkl) {
            const int kk = c * 2 + kkl;
            bf16x8 a = *(const bf16x8*)(rp + kkl * 32 + koff);
            #pragma unroll
            for (int n = 0; n < 8; ++n) {
                bf16x8 b = *(const bf16x8*)(pW1 + (size_t)((kk * 8 + n) * 64 + lane) * 8);
                acc[n] = MFMA16(a, b, acc[n]);
            }
        }
    }

    // ---- hid = relu(acc + b1) -> wave-private LDS [16][132] bf16 (C-layout -> row-major) ----
    u16* Xw = X[wave];
    #pragma unroll
    for (int n = 0; n < 8; ++n) {
        float bias = eb1[n * 16 + l15];
        #pragma unroll
        for (int r = 0; r < 4; ++r) {
            float v = acc[n][r] + bias;
            Xw[(l4 * 4 + r) * 132 + n * 16 + l15] = f2bf(v > 0.f ? v : 0.f);
        }
    }
    asm volatile("s_waitcnt lgkmcnt(0)" ::: "memory");   // wave-private: writes visible to own reads

    // ---- GEMM2: [16 x 128] @ [128 x 64] ----
    f32x4 acc2[4] = {};
    #pragma unroll
    for (int kk = 0; kk < 4; ++kk) {
        bf16x8 a = *(const bf16x8*)(Xw + l15 * 132 + kk * 32 + koff);
        #pragma unroll
        for (int nf = 0; nf < 4; ++nf) {
            bf16x8 b = *(const bf16x8*)(pW2 + (size_t)((kk * 4 + nf) * 64 + lane) * 8);
            acc2[nf] = MFMA16(a, b, acc2[nf]);
        }
    }
    asm volatile("s_waitcnt lgkmcnt(0)" ::: "memory");   // A-reads complete before overwrite

    // ---- e_new + b2 -> wave-private f32 [16][66], then coalesced bf16 store ----
    float* Xf = (float*)Xw;
    #pragma unroll
    for (int nf = 0; nf < 4; ++nf) {
        float bias = eb2[nf * 16 + l15];
        #pragma unroll
        for (int r = 0; r < 4; ++r)
            Xf[(l4 * 4 + r) * 66 + nf * 16 + l15] = acc2[nf][r] + bias;
    }
    asm volatile("s_waitcnt lgkmcnt(0)" ::: "memory");
    {
        int row = lane >> 2, c0 = (lane & 3) * 16;
        const float* s = Xf + row * 66 + c0;
        u16* dst = efn + (size_t)(tile0 + m0 + row) * 64 + c0;
        #pragma unroll
        for (int j = 0; j < 4; ++j) {
            ushort4 o;
            o.x = f2bf(s[j * 4 + 0]); o.y = f2bf(s[j * 4 + 1]);
            o.z = f2bf(s[j * 4 + 2]); o.w = f2bf(s[j * 4 + 3]);
            *(ushort4*)(dst + j * 4) = o;
        }
    }
}

// ---------------- node update: contiguous segmented sum (edges in CSR order) ----------------
// 16 nodes/block, one node per 16-lane group; rows starts[n]..starts[n+1] are ADJACENT in enewp.
__global__ __launch_bounds__(256) void node_update(
    const u16* __restrict__ enewp,
    const int* __restrict__ starts,
    const float* __restrict__ Wn, const float* __restrict__ bn,
    u16* __restrict__ nfn)
{
    __shared__ float Wns[64 * 64];
    int tid = threadIdx.x;
    for (int i = tid; i < 4096; i += 256) Wns[i] = Wn[i];
    __syncthreads();
    const int l = tid & 63;
    const int q = l & 15;
    const int base = l & 48;
    const int n = blockIdx.x * 16 + (tid >> 4);
    if (n >= NN) return;
    const int s0 = starts[n], s1 = starts[n + 1];
    const int cnt = s1 - s0;
    const u16* p = enewp + (size_t)s0 * 64 + q * 4;
    float a0 = 0.f, a1 = 0.f, a2 = 0.f, a3 = 0.f;
    int i = 0;
    for (; i + 4 <= cnt; i += 4) {
        ushort4 v0 = *(const ushort4*)(p + (i + 0) * 64);
        ushort4 v1 = *(const ushort4*)(p + (i + 1) * 64);
        ushort4 v2 = *(const ushort4*)(p + (i + 2) * 64);
        ushort4 v3 = *(const ushort4*)(p + (i + 3) * 64);
        a0 += bf2f(v0.x) + bf2f(v1.x) + bf2f(v2.x) + bf2f(v3.x);
        a1 += bf2f(v0.y) + bf2f(v1.y) + bf2f(v2.y) + bf2f(v3.y);
        a2 += bf2f(v0.z) + bf2f(v1.z) + bf2f(v2.z) + bf2f(v3.z);
        a3 += bf2f(v0.w) + bf2f(v1.w) + bf2f(v2.w) + bf2f(v3.w);
    }
    for (; i < cnt; ++i) {
        ushort4 v0 = *(const ushort4*)(p + i * 64);
        a0 += bf2f(v0.x); a1 += bf2f(v0.y); a2 += bf2f(v0.z); a3 += bf2f(v0.w);
    }
    const float4 bb = *(const float4*)(bn + q * 4);
    float o0 = bb.x, o1 = bb.y, o2 = bb.z, o3 = bb.w;
    #pragma unroll
    for (int hq = 0; hq < 16; ++hq) {
        int src = base | hq;
        float b0 = __shfl(a0, src), b1 = __shfl(a1, src);
        float b2 = __shfl(a2, src), b3 = __shfl(a3, src);
        const float4 w0 = *(const float4*)(Wns + (hq * 4 + 0) * 64 + q * 4);
        const float4 w1 = *(const float4*)(Wns + (hq * 4 + 1) * 64 + q * 4);
        const float4 w2 = *(const float4*)(Wns + (hq * 4 + 2) * 64 + q * 4);
        const float4 w3 = *(const float4*)(Wns + (hq * 4 + 3) * 64 + q * 4);
        o0 += b0 * w0.x + b1 * w1.x + b2 * w2.x + b3 * w3.x;
        o1 += b0 * w0.y + b1 * w1.y + b2 * w2.y + b3 * w3.y;
        o2 += b0 * w0.z + b1 * w1.z + b2 * w2.z + b3 * w3.z;
        o3 += b0 * w0.w + b1 * w1.w + b2 * w2.w + b3 * w3.w;
    }
    ushort4 o;
    o.x = f2bf(o0 > 0.f ? o0 : 0.f);
    o.y = f2bf(o1 > 0.f ? o1 : 0.f);
    o.z = f2bf(o2 > 0.f ? o2 : 0.f);
    o.w = f2bf(o3 > 0.f ? o3 : 0.f);
    *(ushort4*)(nfn + (size_t)n * 64 + q * 4) = o;
}

// ---------------- edge head (MFMA), scatter to original edge id ----------------
__global__ __launch_bounds__(256) void edge_head(
    const u16* __restrict__ ef, const int* __restrict__ eids,
    const u16* __restrict__ pW1, const float* __restrict__ b1,
    const float* __restrict__ W2, const float* __restrict__ b2, float* __restrict__ out)
{
    __shared__ alignas(16) u16 A[64 * 72];
    int tid = threadIdx.x;
    int tile0 = blockIdx.x * 64;
    #pragma unroll
    for (int it = 0; it < 2; ++it) {
        int u = it * 256 + tid;
        int row = u >> 3, sub = u & 7;
        uint4 v = *(const uint4*)(ef + (size_t)(tile0 + row) * 64 + sub * 8);
        *(uint4*)(A + row * 72 + sub * 8) = v;
    }
    __syncthreads();
    int wave = tid >> 6, lane = tid & 63, l15 = lane & 15, l4 = lane >> 4;
    int m0 = wave * 16;
    f32x4 acc[2] = {};
    #pragma unroll
    for (int kk = 0; kk < 2; ++kk) {
        bf16x8 a = *(const bf16x8*)(A + (m0 + l15) * 72 + kk * 32 + l4 * 8);
        #pragma unroll
        for (int nf = 0; nf < 2; ++nf) {
            bf16x8 b = *(const bf16x8*)(pW1 + (size_t)((kk * 2 + nf) * 64 + lane) * 8);
            acc[nf] = MFMA16(a, b, acc[nf]);
        }
    }
    float bias2 = b2[0];
    #pragma unroll
    for (int r = 0; r < 4; ++r) {
        float p = 0.f;
        #pragma unroll
        for (int nf = 0; nf < 2; ++nf) {
            int col = nf * 16 + l15;
            float h = acc[nf][r] + b1[col];
            p += (h > 0.f ? h : 0.f) * W2[col];
        }
        p += __shfl_xor(p, 1); p += __shfl_xor(p, 2);
        p += __shfl_xor(p, 4); p += __shfl_xor(p, 8);
        if (l15 == 0) out[eids[tile0 + m0 + l4 * 4 + r]] = p + bias2;
    }
}

// ---------------- node head ----------------
__global__ void node_head(const u16* __restrict__ nf,
                          const float* __restrict__ ncW1, const float* __restrict__ ncb1,
                          const float* __restrict__ ncW2, const float* __restrict__ ncb2,
                          const float* __restrict__ clW1, const float* __restrict__ clb1,
                          const float* __restrict__ clW2, const float* __restrict__ clb2,
                          float* __restrict__ outN, float* __restrict__ outC) {
    __shared__ float sNW1[2048], sCW1[2048], sCW2[32 * 17];
    __shared__ float sNb1[32], sCb1[32], sNW2[32], sCb2[17];
    int tid = threadIdx.x;
    for (int i = tid; i < 2048; i += 256) { sNW1[i] = ncW1[i]; sCW1[i] = clW1[i]; }
    for (int i = tid; i < 544; i += 256) sCW2[i] = clW2[i];
    if (tid < 32) { sNb1[tid] = ncb1[tid]; sCb1[tid] = clb1[tid]; sNW2[tid] = ncW2[tid]; }
    if (tid < 17) sCb2[tid] = clb2[tid];
    __syncthreads();
    int n = blockIdx.x * 256 + tid;
    if (n >= NN) return;
    const u16* r = nf + (size_t)n * 64;
    float v[64];
    for (int k4 = 0; k4 < 16; ++k4) {
        ushort4 q = *(const ushort4*)(r + k4 * 4);
        v[k4 * 4 + 0] = bf2f(q.x); v[k4 * 4 + 1] = bf2f(q.y);
        v[k4 * 4 + 2] = bf2f(q.z); v[k4 * 4 + 3] = bf2f(q.w);
    }
    float h[32];
    #pragma unroll
    for (int j = 0; j < 32; ++j) h[j] = sNb1[j];
    for (int k = 0; k < 64; ++k) {
        float vk = v[k];
        #pragma unroll
        for (int j = 0; j < 32; ++j) h[j] += vk * sNW1[k * 32 + j];
    }
    float o = ncb2[0];
    #pragma unroll
    for (int j = 0; j < 32; ++j) o += (h[j] > 0.f ? h[j] : 0.f) * sNW2[j];
    outN[n] = o;
    #pragma unroll
    for (int j = 0; j < 32; ++j) h[j] = sCb1[j];
    for (int k = 0; k < 64; ++k) {
        float vk = v[k];
        #pragma unroll
        for (int j = 0; j < 32; ++j) h[j] += vk * sCW1[k * 32 + j];
    }
    float oc[17];
    #pragma unroll
    for (int c = 0; c < 17; ++c) oc[c] = sCb2[c];
    #pragma unroll
    for (int j = 0; j < 32; ++j) {
        float hr = h[j] > 0.f ? h[j] : 0.f;
        #pragma unroll
        for (int c = 0; c < 17; ++c) oc[c] += hr * sCW2[j * 17 + c];
    }
    #pragma unroll
    for (int c = 0; c < 17; ++c) outC[(size_t)n * 17 + c] = oc[c];
}

// ---------------- launch ----------------
extern "C" void kernel_launch(void* const* d_in, const int* in_sizes, int n_in,
                              void* d_out, int out_size, void* d_ws, size_t ws_size,
                              hipStream_t stream) {
    const float* x     = (const float*)d_in[0];
    const float* ea    = (const float*)d_in[1];
    const int*   eidx  = (const int*)d_in[2];
    const float* neW1  = (const float*)d_in[4];
    const float* neb1  = (const float*)d_in[5];
    const float* neW2  = (const float*)d_in[6];
    const float* neb2  = (const float*)d_in[7];
    const float* eeW1  = (const float*)d_in[8];
    const float* eeb1  = (const float*)d_in[9];
    const float* eeW2  = (const float*)d_in[10];
    const float* eeb2  = (const float*)d_in[11];
    const float* mpW1  = (const float*)d_in[12];
    const float* mpb1  = (const float*)d_in[13];
    const float* mpW2  = (const float*)d_in[14];
    const float* mpb2  = (const float*)d_in[15];
    const float* mpnW  = (const float*)d_in[16];
    const float* mpnb  = (const float*)d_in[17];
    const float* ecW1  = (const float*)d_in[18];
    const float* ecb1  = (const float*)d_in[19];
    const float* ecW2  = (const float*)d_in[20];
    const float* ecb2  = (const float*)d_in[21];
    const float* ncW1  = (const float*)d_in[22];
    const float* ncb1  = (const float*)d_in[23];
    const float* ncW2  = (const float*)d_in[24];
    const float* ncb2  = (const float*)d_in[25];
    const float* clW1  = (const float*)d_in[26];
    const float* clb1  = (const float*)d_in[27];
    const float* clW2  = (const float*)d_in[28];
    const float* clb2  = (const float*)d_in[29];

    char* w = (char*)d_ws;
    size_t used = 0;
    auto alloc = [&](size_t b) {
        char* p = w + used; used += (b + 255) & ~(size_t)255; return p;
    };
    u16* nf0  = (u16*)alloc((size_t)NN * 64 * 2);
    u16* nfW  = (u16*)alloc((size_t)NN * 64 * 2);
    u16* ef0  = (u16*)alloc((size_t)EE * 64 * 2);   // PERMUTED (CSR position order)
    u16* efW  = (u16*)alloc((size_t)EE * 64 * 2);   // PERMUTED
    u16* pmW1 = (u16*)alloc(49152 * 2);   // mp edge MLP L1: K=384 N=128
    u16* pmW2 = (u16*)alloc(8192 * 2);    // mp edge MLP L2: K=128 N=64
    u16* pnW1 = (u16*)alloc(8192 * 2);    // node embed L1:  K=128 N=64
    u16* pnW2 = (u16*)alloc(4096 * 2);    // node embed L2:  K=64  N=64
    u16* peW1 = (u16*)alloc(2048 * 2);    // edge embed L1:  K=19->32 N=64
    u16* peW2 = (u16*)alloc(4096 * 2);    // edge embed L2:  K=64  N=64
    u16* pcW1 = (u16*)alloc(2048 * 2);    // edge head L1:   K=64  N=32
    int* cnt    = (int*)alloc((size_t)NN * 4);       // reused as `cur`
    int* starts = (int*)alloc((size_t)(NN + 1) * 4);
    int* eids   = (int*)alloc((size_t)EE * 4);
    int* psrc   = (int*)alloc((size_t)EE * 4);
    int* pdst   = (int*)alloc((size_t)EE * 4);
    if (used > ws_size) return;

    pack_frag<<<192, 256, 0, stream>>>(mpW1, pmW1, 384, 128);
    pack_frag<<<32, 256, 0, stream>>>(mpW2, pmW2, 128, 64);
    pack_frag<<<32, 256, 0, stream>>>(neW1, pnW1, 128, 64);
    pack_frag<<<16, 256, 0, stream>>>(neW2, pnW2, 64, 64);
    pack_frag<<<8, 256, 0, stream>>>(eeW1, peW1, 19, 64);
    pack_frag<<<16, 256, 0, stream>>>(eeW2, peW2, 64, 64);
    pack_frag<<<8, 256, 0, stream>>>(ecW1, pcW1, 64, 32);

    // CSR build first (embed_edge + edge loop consume the permutation)
    zero_cnt<<<(NN + 255) / 256, 256, 0, stream>>>(cnt);
    count_deg<<<EE / 256, 256, 0, stream>>>(eidx, cnt);
    scan_k<<<1, 1024, 0, stream>>>(cnt, starts);
    init_cur<<<(NN + 255) / 256, 256, 0, stream>>>(starts, cnt);
    scatter_e<<<EE / 256, 256, 0, stream>>>(eidx, cnt, eids);
    build_perm<<<EE / 256, 256, 0, stream>>>(eidx, eids, psrc, pdst);

    embed_mfma_node<<<(NN + 63) / 64, 256, 0, stream>>>(x, pnW1, neb1, pnW2, neb2, nf0);
    embed_mfma_edge<<<EE / 64, 256, 0, stream>>>(ea, eids, peW1, eeb1, peW2, eeb2, ef0);

    float* outE = (float*)d_out;
    float* outN = outE + EE;
    float* outC = outN + NN;

    const u16* nfc = nf0;
    const u16* efc = ef0;
    for (int s = 0; s < 6; ++s) {
        edge_mlp<<<EE / 64, 256, 0, stream>>>(psrc, pdst, nf0, nfc, ef0, efc,
                                              pmW1, pmW2, mpb1, mpb2, efW);
        node_update<<<(NN + 15) / 16, 256, 0, stream>>>(efW, starts, mpnW, mpnb, nfW);
        if (s == 3)
            edge_head<<<EE / 64, 256, 0, stream>>>(efW, eids, pcW1, ecb1, ecW2, ecb2, outE);
        efc = efW;
        nfc = nfW;
    }
    node_head<<<(NN + 255) / 256, 256, 0, stream>>>(nfc, ncW1, ncb1, ncW2, ncb2,
                                                    clW1, clb1, clW2, clb2, outN, outC);
    (void)in_sizes; (void)n_in; (void)out_size;
}

// Round 8
// 1396.501 us; speedup vs baseline: 1.3224x; 1.3224x over previous
//
#include <hip/hip_runtime.h>

#define NN 50000
#define EE 800000

typedef unsigned short u16;
typedef __attribute__((ext_vector_type(8))) short bf16x8;
typedef __attribute__((ext_vector_type(4))) float f32x4;

#define MFMA16(a, b, c) __builtin_amdgcn_mfma_f32_16x16x32_bf16(a, b, c, 0, 0, 0)

__device__ __forceinline__ float bf2f(u16 v) {
    union { unsigned u; float f; } x; x.u = ((unsigned)v) << 16; return x.f;
}
__device__ __forceinline__ u16 f2bf(float f) {
    union { float f; unsigned u; } x; x.f = f;
    unsigned r = x.u + 0x7FFFu + ((x.u >> 16) & 1u);
    return (u16)(r >> 16);
}
__device__ __forceinline__ void gl_lds16(const u16* g, u16* l) {
    __builtin_amdgcn_global_load_lds((const __attribute__((address_space(1))) void*)g,
                                     (__attribute__((address_space(3))) void*)l, 16, 0, 0);
}

// ---------------- generic weight packing (fragment-major bf16) ----------------
// dst[kk][nf][lane][t]: k = kk*32 + (lane>>4)*8 + t (zero-padded past K), n = nf*16 + (lane&15)
__global__ void pack_frag(const float* __restrict__ W, u16* __restrict__ dst, int K, int N) {
    int i = blockIdx.x * 256 + threadIdx.x;
    int nfc = N / 16, kkc = (K + 31) / 32;
    int total = kkc * nfc * 512;
    if (i >= total) return;
    int t = i & 7, lane = (i >> 3) & 63;
    int rest = i >> 9;
    int nf = rest % nfc, kk = rest / nfc;
    int k = kk * 32 + (lane >> 4) * 8 + t, n = nf * 16 + (lane & 15);
    dst[i] = (k < K) ? f2bf(W[k * N + n]) : (u16)0;
}

// ---------------- MFMA node embedding ----------------
__global__ __launch_bounds__(256) void embed_mfma_node(
    const float* __restrict__ x, const u16* __restrict__ pW1, const float* __restrict__ b1,
    const u16* __restrict__ pW2, const float* __restrict__ b2, u16* __restrict__ out)
{
    __shared__ alignas(16) u16 A[64 * 136];
    __shared__ alignas(16) u16 Hs[64 * 72];
    int tid = threadIdx.x;
    size_t row0 = (size_t)blockIdx.x * 64;
    #pragma unroll
    for (int it = 0; it < 8; ++it) {
        int u = it * 256 + tid;
        int row = u >> 5, seg = u & 31;
        float4 v = (row0 + row < NN) ? *(const float4*)(x + (row0 + row) * 128 + seg * 4)
                                     : make_float4(0.f, 0.f, 0.f, 0.f);
        ushort4 o; o.x = f2bf(v.x); o.y = f2bf(v.y); o.z = f2bf(v.z); o.w = f2bf(v.w);
        *(ushort4*)(A + row * 136 + seg * 4) = o;
    }
    __syncthreads();
    int wave = tid >> 6, lane = tid & 63, l15 = lane & 15, l4 = lane >> 4;
    int col = wave * 16 + l15;
    f32x4 acc[4] = {};
    #pragma unroll
    for (int kk = 0; kk < 4; ++kk) {
        bf16x8 b = *(const bf16x8*)(pW1 + (size_t)((kk * 4 + wave) * 64 + lane) * 8);
        #pragma unroll
        for (int mi = 0; mi < 4; ++mi) {
            bf16x8 a = *(const bf16x8*)(A + (mi * 16 + l15) * 136 + kk * 32 + l4 * 8);
            acc[mi] = MFMA16(a, b, acc[mi]);
        }
    }
    float bias = b1[col];
    #pragma unroll
    for (int mi = 0; mi < 4; ++mi)
        #pragma unroll
        for (int r = 0; r < 4; ++r) {
            float v = acc[mi][r] + bias;
            Hs[(mi * 16 + l4 * 4 + r) * 72 + col] = f2bf(v > 0.f ? v : 0.f);
        }
    __syncthreads();
    f32x4 acc2[4] = {};
    #pragma unroll
    for (int kk = 0; kk < 2; ++kk) {
        bf16x8 b = *(const bf16x8*)(pW2 + (size_t)((kk * 4 + wave) * 64 + lane) * 8);
        #pragma unroll
        for (int mi = 0; mi < 4; ++mi) {
            bf16x8 a = *(const bf16x8*)(Hs + (mi * 16 + l15) * 72 + kk * 32 + l4 * 8);
            acc2[mi] = MFMA16(a, b, acc2[mi]);
        }
    }
    float bias2 = b2[col];
    __syncthreads();
    #pragma unroll
    for (int mi = 0; mi < 4; ++mi)
        #pragma unroll
        for (int r = 0; r < 4; ++r)
            Hs[(mi * 16 + l4 * 4 + r) * 72 + col] = f2bf(acc2[mi][r] + bias2);
    __syncthreads();
    #pragma unroll
    for (int it = 0; it < 4; ++it) {
        int u = it * 256 + tid;
        int row = u >> 4, c4 = (u & 15) * 4;
        if (row0 + row < NN) {
            ushort4 o = *(const ushort4*)(Hs + row * 72 + c4);
            *(ushort4*)(out + (row0 + row) * 64 + c4) = o;
        }
    }
}

// ---------------- MFMA edge embedding (gathers ea rows by eids -> writes PERMUTED ef0) ----------------
__global__ __launch_bounds__(256) void embed_mfma_edge(
    const float* __restrict__ ea, const int* __restrict__ eids,
    const u16* __restrict__ pW1, const float* __restrict__ b1,
    const u16* __restrict__ pW2, const float* __restrict__ b2, u16* __restrict__ out)
{
    __shared__ alignas(16) u16 A[64 * 40];
    __shared__ alignas(16) u16 Hs[64 * 72];
    __shared__ int eid_s[64];
    int tid = threadIdx.x;
    size_t row0 = (size_t)blockIdx.x * 64;
    if (tid < 64) eid_s[tid] = eids[row0 + tid];
    __syncthreads();
    #pragma unroll
    for (int it = 0; it < 8; ++it) {
        int u = it * 256 + tid;
        int row = u >> 5, k = u & 31;
        float v = (k < 19) ? ea[(size_t)eid_s[row] * 19 + k] : 0.f;
        A[row * 40 + k] = f2bf(v);
    }
    __syncthreads();
    int wave = tid >> 6, lane = tid & 63, l15 = lane & 15, l4 = lane >> 4;
    int col = wave * 16 + l15;
    f32x4 acc[4] = {};
    {
        bf16x8 b = *(const bf16x8*)(pW1 + (size_t)(wave * 64 + lane) * 8);
        #pragma unroll
        for (int mi = 0; mi < 4; ++mi) {
            bf16x8 a = *(const bf16x8*)(A + (mi * 16 + l15) * 40 + l4 * 8);
            acc[mi] = MFMA16(a, b, acc[mi]);
        }
    }
    float bias = b1[col];
    #pragma unroll
    for (int mi = 0; mi < 4; ++mi)
        #pragma unroll
        for (int r = 0; r < 4; ++r) {
            float v = acc[mi][r] + bias;
            Hs[(mi * 16 + l4 * 4 + r) * 72 + col] = f2bf(v > 0.f ? v : 0.f);
        }
    __syncthreads();
    f32x4 acc2[4] = {};
    #pragma unroll
    for (int kk = 0; kk < 2; ++kk) {
        bf16x8 b = *(const bf16x8*)(pW2 + (size_t)((kk * 4 + wave) * 64 + lane) * 8);
        #pragma unroll
        for (int mi = 0; mi < 4; ++mi) {
            bf16x8 a = *(const bf16x8*)(Hs + (mi * 16 + l15) * 72 + kk * 32 + l4 * 8);
            acc2[mi] = MFMA16(a, b, acc2[mi]);
        }
    }
    float bias2 = b2[col];
    __syncthreads();
    #pragma unroll
    for (int mi = 0; mi < 4; ++mi)
        #pragma unroll
        for (int r = 0; r < 4; ++r)
            Hs[(mi * 16 + l4 * 4 + r) * 72 + col] = f2bf(acc2[mi][r] + bias2);
    __syncthreads();
    #pragma unroll
    for (int it = 0; it < 4; ++it) {
        int u = it * 256 + tid;
        int row = u >> 4, c4 = (u & 15) * 4;
        ushort4 o = *(const ushort4*)(Hs + row * 72 + c4);
        *(ushort4*)(out + (row0 + row) * 64 + c4) = o;
    }
}

// ---------------- CSR build ----------------
__global__ void zero_cnt(int* __restrict__ cnt) {
    int i = blockIdx.x * 256 + threadIdx.x;
    if (i < NN) cnt[i] = 0;
}
__global__ void count_deg(const int* __restrict__ eidx, int* __restrict__ cnt) {
    int e = blockIdx.x * 256 + threadIdx.x;
    if (e < EE) atomicAdd(&cnt[eidx[EE + e]], 1);
}
__global__ void scan_k(const int* __restrict__ cnt, int* __restrict__ starts) {
    __shared__ int part[1024];
    int t = threadIdx.x;
    const int chunk = (NN + 1023) / 1024;
    int lo = t * chunk, hi = lo + chunk; if (hi > NN) hi = NN;
    if (lo > NN) lo = NN;
    int s = 0;
    for (int i = lo; i < hi; ++i) s += cnt[i];
    part[t] = s;
    __syncthreads();
    for (int off = 1; off < 1024; off <<= 1) {
        int v = part[t];
        int add = (t >= off) ? part[t - off] : 0;
        __syncthreads();
        part[t] = v + add;
        __syncthreads();
    }
    int run = (t == 0) ? 0 : part[t - 1];
    for (int i = lo; i < hi; ++i) { starts[i] = run; run += cnt[i]; }
    if (t == 1023) starts[NN] = EE;
}
__global__ void init_cur(const int* __restrict__ starts, int* __restrict__ cur) {
    int i = blockIdx.x * 256 + threadIdx.x;
    if (i < NN) cur[i] = starts[i];
}
__global__ void scatter_e(const int* __restrict__ eidx, int* __restrict__ cur,
                          int* __restrict__ eids) {
    int e = blockIdx.x * 256 + threadIdx.x;
    if (e < EE) {
        int pos = atomicAdd(&cur[eidx[EE + e]], 1);
        eids[pos] = e;
    }
}
__global__ void build_perm(const int* __restrict__ eidx, const int* __restrict__ eids,
                           int* __restrict__ psrc, int* __restrict__ pdst) {
    int j = blockIdx.x * 256 + threadIdx.x;
    if (j < EE) {
        int e = eids[j];
        psrc[j] = eidx[e];
        pdst[j] = eidx[EE + e];
    }
}

// ---------------- fused edge MLP v10: v6 pipeline, 4 recycled buffers (32KB), fused head ----------------
// Identical schedule to the verified v6 kernel except chunks 4/5 recycle buffers 0/1 after
// their last reader (post-phase-0/1 barriers guarantee all waves are done before the recycle
// DMA is issued). LDS 48KB -> 32KB => 4 blocks/CU. vmcnt ladder: 6,6,6,4,2,0.
// Hid overlays buf2-3 (last read phase 3; all waves past the pre-phase-5 barrier when written).
// EnF overlays buf0-1 (last read phase 5; all waves past the Hid __syncthreads when written).
// At s==3 the edge head is computed inline from EnF (A = f2bf(EnF), bit-identical to the
// standalone edge_head kernel) - saves a full 102MB-read dispatch.
__global__ __launch_bounds__(256, 4) void edge_mlp(
    const int* __restrict__ psrc, const int* __restrict__ pdst,
    const u16* __restrict__ nf0, const u16* __restrict__ nfc,
    const u16* __restrict__ ef0, const u16* __restrict__ efc,
    const u16* __restrict__ pW1, const u16* __restrict__ pW2,
    const float* __restrict__ eb1, const float* __restrict__ eb2,
    u16* __restrict__ efn,
    const int* __restrict__ eids, const u16* __restrict__ pcW1,
    const float* __restrict__ hb1, const float* __restrict__ hW2,
    const float* __restrict__ hb2, float* __restrict__ outE, int doHead)
{
    __shared__ alignas(16) u16 Chunk[4][64 * 64];   // 32KB
    const int tid = threadIdx.x;
    const int tile0 = blockIdx.x * 64;
    const int wave = tid >> 6, lane = tid & 63;
    const int l15 = lane & 15, l4 = lane >> 4;

    // per-lane DMA geometry: 8 lanes cover one row (8 x 16B units); lane owns rows r0,r1
    const int r0 = wave * 16 + (lane >> 3);
    const int r1 = r0 + 8;
    const int u_ = lane & 7;
    const int su0 = u_ ^ (r0 & 7);        // pre-swizzled source unit (XOR involution)
    const int su1 = u_ ^ (r1 & 7);
    const int is0 = psrc[tile0 + r0] * 64;
    const int is1 = psrc[tile0 + r1] * 64;
    const int id0 = pdst[tile0 + r0] * 64;
    const int id1 = pdst[tile0 + r1] * 64;

    // W1 fragment preload (order pinned before DMA issue; compiler may still reload in-loop,
    // same behavior as the verified v6 kernel)
    bf16x8 bw[24];
    #pragma unroll
    for (int kk = 0; kk < 12; ++kk) {
        bw[kk * 2 + 0] = *(const bf16x8*)(pW1 + (size_t)((kk * 8 + wave * 2 + 0) * 64 + lane) * 8);
        bw[kk * 2 + 1] = *(const bf16x8*)(pW1 + (size_t)((kk * 8 + wave * 2 + 1) * 64 + lane) * 8);
    }
    #pragma unroll
    for (int i = 0; i < 24; ++i) asm volatile("" : "+v"(bw[i]));
    __builtin_amdgcn_sched_barrier(0);

    // ---- issue chunks 0..3 (8 DMA loads/lane in flight) ----
    #pragma unroll
    for (int c = 0; c < 4; ++c) {
        const u16 *b0, *b1;
        if (c == 0)      { b0 = nf0 + is0; b1 = nf0 + is1; }
        else if (c == 1) { b0 = nfc + is0; b1 = nfc + is1; }
        else if (c == 2) { b0 = nf0 + id0; b1 = nf0 + id1; }
        else             { b0 = nfc + id0; b1 = nfc + id1; }
        u16* l0 = (u16*)Chunk + c * 4096 + wave * 1024;   // + lane*16B by HW; row r1 at +512
        gl_lds16(b0 + su0 * 8, l0);
        gl_lds16(b1 + su1 * 8, l0 + 512);
    }
    __builtin_amdgcn_sched_barrier(0);

    f32x4 acc[4][2] = {};
    auto gemm_chunk = [&](int buf, int kk0) {
        const char* Cb = (const char*)Chunk + buf * 8192;
        #pragma unroll
        for (int kkl = 0; kkl < 2; ++kkl) {
            #pragma unroll
            for (int mi = 0; mi < 4; ++mi) {
                int row = mi * 16 + l15;
                bf16x8 a = *(const bf16x8*)(Cb + row * 128 + ((kkl * 64 + l4 * 16) ^ ((row & 7) << 4)));
                acc[mi][0] = MFMA16(a, bw[(kk0 + kkl) * 2 + 0], acc[mi][0]);
                acc[mi][1] = MFMA16(a, bw[(kk0 + kkl) * 2 + 1], acc[mi][1]);
            }
        }
    };

    // phase 0 (buf0 = nf0[src])
    asm volatile("s_waitcnt vmcnt(6)" ::: "memory");
    __builtin_amdgcn_s_barrier();
    __builtin_amdgcn_sched_barrier(0);
    gemm_chunk(0, 0);
    __builtin_amdgcn_s_barrier();          // all waves done reading buf0
    __builtin_amdgcn_sched_barrier(0);
    {   // recycle buf0 for ef0 chunk
        u16* l0 = (u16*)Chunk + wave * 1024;
        gl_lds16(ef0 + (size_t)(tile0 + r0) * 64 + su0 * 8, l0);
        gl_lds16(ef0 + (size_t)(tile0 + r1) * 64 + su1 * 8, l0 + 512);
    }
    __builtin_amdgcn_sched_barrier(0);
    // phase 1 (buf1 = nfc[src])
    asm volatile("s_waitcnt vmcnt(6)" ::: "memory");
    __builtin_amdgcn_s_barrier();
    __builtin_amdgcn_sched_barrier(0);
    gemm_chunk(1, 2);
    __builtin_amdgcn_s_barrier();          // all waves done reading buf1
    __builtin_amdgcn_sched_barrier(0);
    {   // recycle buf1 for efc chunk
        u16* l0 = (u16*)Chunk + 4096 + wave * 1024;
        gl_lds16(efc + (size_t)(tile0 + r0) * 64 + su0 * 8, l0);
        gl_lds16(efc + (size_t)(tile0 + r1) * 64 + su1 * 8, l0 + 512);
    }
    __builtin_amdgcn_sched_barrier(0);
    // phase 2 (buf2 = nf0[dst])
    asm volatile("s_waitcnt vmcnt(6)" ::: "memory");
    __builtin_amdgcn_s_barrier();
    __builtin_amdgcn_sched_barrier(0);
    gemm_chunk(2, 4);
    // phase 3 (buf3 = nfc[dst])
    asm volatile("s_waitcnt vmcnt(4)" ::: "memory");
    __builtin_amdgcn_s_barrier();
    __builtin_amdgcn_sched_barrier(0);
    gemm_chunk(3, 6);
    // phase 4 (buf0 = ef0)
    asm volatile("s_waitcnt vmcnt(2)" ::: "memory");
    __builtin_amdgcn_s_barrier();
    __builtin_amdgcn_sched_barrier(0);
    gemm_chunk(0, 8);
    // phase 5 (buf1 = efc)
    asm volatile("s_waitcnt vmcnt(0)" ::: "memory");
    __builtin_amdgcn_s_barrier();
    __builtin_amdgcn_sched_barrier(0);
    gemm_chunk(1, 10);

    // hidden = relu(acc + b1) -> HidB (overlays buf2..buf3; their last read was phase 3,
    // and every wave is past the pre-phase-5 barrier here)
    char* HidB = (char*)Chunk + 16384;
    #pragma unroll
    for (int nj = 0; nj < 2; ++nj) {
        int col = wave * 32 + nj * 16 + l15;
        float bias = eb1[col];
        #pragma unroll
        for (int mi = 0; mi < 4; ++mi) {
            #pragma unroll
            for (int r = 0; r < 4; ++r) {
                int row = mi * 16 + l4 * 4 + r;
                float v = acc[mi][nj][r] + bias;
                v = v > 0.f ? v : 0.f;
                *(u16*)(HidB + row * 256 + ((col * 2) ^ ((row & 7) << 4))) = f2bf(v);
            }
        }
    }
    __syncthreads();

    // GEMM2: [64x128]@[128x64]; wave owns rows wave*16..+15
    f32x4 acc2[4] = {};
    const int m0 = wave * 16;
    #pragma unroll
    for (int kk = 0; kk < 4; ++kk) {
        int row = m0 + l15;
        bf16x8 a = *(const bf16x8*)(HidB + row * 256 + ((kk * 64 + l4 * 16) ^ ((row & 7) << 4)));
        #pragma unroll
        for (int nf = 0; nf < 4; ++nf) {
            bf16x8 b = *(const bf16x8*)(pW2 + (size_t)((kk * 4 + nf) * 64 + lane) * 8);
            acc2[nf] = MFMA16(a, b, acc2[nf]);
        }
    }

    // e_new staging (f32 [64][64] overlays buf0..buf1; last read phase 5, all waves past
    // the Hid __syncthreads), then coalesced bf16 store
    float* EnF = (float*)Chunk;
    #pragma unroll
    for (int nf = 0; nf < 4; ++nf) {
        int col = nf * 16 + l15;
        float bias = eb2[col];
        #pragma unroll
        for (int r = 0; r < 4; ++r) {
            int row = m0 + l4 * 4 + r;
            EnF[row * 64 + col] = acc2[nf][r] + bias;
        }
    }
    __syncthreads();
    #pragma unroll
    for (int rep = 0; rep < 4; ++rep) {
        int u = rep * 256 + tid;
        int el = u >> 4, d0 = (u & 15) * 4;
        const float* s = EnF + el * 64 + d0;
        ushort4 o;
        o.x = f2bf(s[0]); o.y = f2bf(s[1]); o.z = f2bf(s[2]); o.w = f2bf(s[3]);
        *(ushort4*)(efn + (size_t)(tile0 + el) * 64 + d0) = o;
    }

    // ---- fused edge head (s==3 only): A = f2bf(EnF), bit-identical to edge_head kernel ----
    if (doHead) {
        f32x4 hacc[2] = {};
        #pragma unroll
        for (int kk = 0; kk < 2; ++kk) {
            const float* s = EnF + (m0 + l15) * 64 + kk * 32 + l4 * 8;
            bf16x8 a;
            #pragma unroll
            for (int j = 0; j < 8; ++j) a[j] = (short)f2bf(s[j]);
            #pragma unroll
            for (int nf = 0; nf < 2; ++nf) {
                bf16x8 b = *(const bf16x8*)(pcW1 + (size_t)((kk * 2 + nf) * 64 + lane) * 8);
                hacc[nf] = MFMA16(a, b, hacc[nf]);
            }
        }
        float bias2 = hb2[0];
        #pragma unroll
        for (int r = 0; r < 4; ++r) {
            float p = 0.f;
            #pragma unroll
            for (int nf = 0; nf < 2; ++nf) {
                int col = nf * 16 + l15;
                float h = hacc[nf][r] + hb1[col];
                p += (h > 0.f ? h : 0.f) * hW2[col];
            }
            p += __shfl_xor(p, 1); p += __shfl_xor(p, 2);
            p += __shfl_xor(p, 4); p += __shfl_xor(p, 8);
            if (l15 == 0) outE[eids[tile0 + m0 + l4 * 4 + r]] = p + bias2;
        }
    }
}

// ---------------- node update: contiguous segmented sum (edges in CSR order) ----------------
// 16 nodes/block, one node per 16-lane group; rows starts[n]..starts[n+1] are ADJACENT in enewp.
__global__ __launch_bounds__(256) void node_update(
    const u16* __restrict__ enewp,
    const int* __restrict__ starts,
    const float* __restrict__ Wn, const float* __restrict__ bn,
    u16* __restrict__ nfn)
{
    __shared__ float Wns[64 * 64];
    int tid = threadIdx.x;
    for (int i = tid; i < 4096; i += 256) Wns[i] = Wn[i];
    __syncthreads();
    const int l = tid & 63;
    const int q = l & 15;
    const int base = l & 48;
    const int n = blockIdx.x * 16 + (tid >> 4);
    if (n >= NN) return;
    const int s0 = starts[n], s1 = starts[n + 1];
    const int cnt = s1 - s0;
    const u16* p = enewp + (size_t)s0 * 64 + q * 4;
    float a0 = 0.f, a1 = 0.f, a2 = 0.f, a3 = 0.f;
    int i = 0;
    for (; i + 4 <= cnt; i += 4) {
        ushort4 v0 = *(const ushort4*)(p + (i + 0) * 64);
        ushort4 v1 = *(const ushort4*)(p + (i + 1) * 64);
        ushort4 v2 = *(const ushort4*)(p + (i + 2) * 64);
        ushort4 v3 = *(const ushort4*)(p + (i + 3) * 64);
        a0 += bf2f(v0.x) + bf2f(v1.x) + bf2f(v2.x) + bf2f(v3.x);
        a1 += bf2f(v0.y) + bf2f(v1.y) + bf2f(v2.y) + bf2f(v3.y);
        a2 += bf2f(v0.z) + bf2f(v1.z) + bf2f(v2.z) + bf2f(v3.z);
        a3 += bf2f(v0.w) + bf2f(v1.w) + bf2f(v2.w) + bf2f(v3.w);
    }
    for (; i < cnt; ++i) {
        ushort4 v0 = *(const ushort4*)(p + i * 64);
        a0 += bf2f(v0.x); a1 += bf2f(v0.y); a2 += bf2f(v0.z); a3 += bf2f(v0.w);
    }
    const float4 bb = *(const float4*)(bn + q * 4);
    float o0 = bb.x, o1 = bb.y, o2 = bb.z, o3 = bb.w;
    #pragma unroll
    for (int hq = 0; hq < 16; ++hq) {
        int src = base | hq;
        float b0 = __shfl(a0, src), b1 = __shfl(a1, src);
        float b2 = __shfl(a2, src), b3 = __shfl(a3, src);
        const float4 w0 = *(const float4*)(Wns + (hq * 4 + 0) * 64 + q * 4);
        const float4 w1 = *(const float4*)(Wns + (hq * 4 + 1) * 64 + q * 4);
        const float4 w2 = *(const float4*)(Wns + (hq * 4 + 2) * 64 + q * 4);
        const float4 w3 = *(const float4*)(Wns + (hq * 4 + 3) * 64 + q * 4);
        o0 += b0 * w0.x + b1 * w1.x + b2 * w2.x + b3 * w3.x;
        o1 += b0 * w0.y + b1 * w1.y + b2 * w2.y + b3 * w3.y;
        o2 += b0 * w0.z + b1 * w1.z + b2 * w2.z + b3 * w3.z;
        o3 += b0 * w0.w + b1 * w1.w + b2 * w2.w + b3 * w3.w;
    }
    ushort4 o;
    o.x = f2bf(o0 > 0.f ? o0 : 0.f);
    o.y = f2bf(o1 > 0.f ? o1 : 0.f);
    o.z = f2bf(o2 > 0.f ? o2 : 0.f);
    o.w = f2bf(o3 > 0.f ? o3 : 0.f);
    *(ushort4*)(nfn + (size_t)n * 64 + q * 4) = o;
}

// ---------------- node head ----------------
__global__ void node_head(const u16* __restrict__ nf,
                          const float* __restrict__ ncW1, const float* __restrict__ ncb1,
                          const float* __restrict__ ncW2, const float* __restrict__ ncb2,
                          const float* __restrict__ clW1, const float* __restrict__ clb1,
                          const float* __restrict__ clW2, const float* __restrict__ clb2,
                          float* __restrict__ outN, float* __restrict__ outC) {
    __shared__ float sNW1[2048], sCW1[2048], sCW2[32 * 17];
    __shared__ float sNb1[32], sCb1[32], sNW2[32], sCb2[17];
    int tid = threadIdx.x;
    for (int i = tid; i < 2048; i += 256) { sNW1[i] = ncW1[i]; sCW1[i] = clW1[i]; }
    for (int i = tid; i < 544; i += 256) sCW2[i] = clW2[i];
    if (tid < 32) { sNb1[tid] = ncb1[tid]; sCb1[tid] = clb1[tid]; sNW2[tid] = ncW2[tid]; }
    if (tid < 17) sCb2[tid] = clb2[tid];
    __syncthreads();
    int n = blockIdx.x * 256 + tid;
    if (n >= NN) return;
    const u16* r = nf + (size_t)n * 64;
    float v[64];
    for (int k4 = 0; k4 < 16; ++k4) {
        ushort4 q = *(const ushort4*)(r + k4 * 4);
        v[k4 * 4 + 0] = bf2f(q.x); v[k4 * 4 + 1] = bf2f(q.y);
        v[k4 * 4 + 2] = bf2f(q.z); v[k4 * 4 + 3] = bf2f(q.w);
    }
    float h[32];
    #pragma unroll
    for (int j = 0; j < 32; ++j) h[j] = sNb1[j];
    for (int k = 0; k < 64; ++k) {
        float vk = v[k];
        #pragma unroll
        for (int j = 0; j < 32; ++j) h[j] += vk * sNW1[k * 32 + j];
    }
    float o = ncb2[0];
    #pragma unroll
    for (int j = 0; j < 32; ++j) o += (h[j] > 0.f ? h[j] : 0.f) * sNW2[j];
    outN[n] = o;
    #pragma unroll
    for (int j = 0; j < 32; ++j) h[j] = sCb1[j];
    for (int k = 0; k < 64; ++k) {
        float vk = v[k];
        #pragma unroll
        for (int j = 0; j < 32; ++j) h[j] += vk * sCW1[k * 32 + j];
    }
    float oc[17];
    #pragma unroll
    for (int c = 0; c < 17; ++c) oc[c] = sCb2[c];
    #pragma unroll
    for (int j = 0; j < 32; ++j) {
        float hr = h[j] > 0.f ? h[j] : 0.f;
        #pragma unroll
        for (int c = 0; c < 17; ++c) oc[c] += hr * sCW2[j * 17 + c];
    }
    #pragma unroll
    for (int c = 0; c < 17; ++c) outC[(size_t)n * 17 + c] = oc[c];
}

// ---------------- launch ----------------
extern "C" void kernel_launch(void* const* d_in, const int* in_sizes, int n_in,
                              void* d_out, int out_size, void* d_ws, size_t ws_size,
                              hipStream_t stream) {
    const float* x     = (const float*)d_in[0];
    const float* ea    = (const float*)d_in[1];
    const int*   eidx  = (const int*)d_in[2];
    const float* neW1  = (const float*)d_in[4];
    const float* neb1  = (const float*)d_in[5];
    const float* neW2  = (const float*)d_in[6];
    const float* neb2  = (const float*)d_in[7];
    const float* eeW1  = (const float*)d_in[8];
    const float* eeb1  = (const float*)d_in[9];
    const float* eeW2  = (const float*)d_in[10];
    const float* eeb2  = (const float*)d_in[11];
    const float* mpW1  = (const float*)d_in[12];
    const float* mpb1  = (const float*)d_in[13];
    const float* mpW2  = (const float*)d_in[14];
    const float* mpb2  = (const float*)d_in[15];
    const float* mpnW  = (const float*)d_in[16];
    const float* mpnb  = (const float*)d_in[17];
    const float* ecW1  = (const float*)d_in[18];
    const float* ecb1  = (const float*)d_in[19];
    const float* ecW2  = (const float*)d_in[20];
    const float* ecb2  = (const float*)d_in[21];
    const float* ncW1  = (const float*)d_in[22];
    const float* ncb1  = (const float*)d_in[23];
    const float* ncW2  = (const float*)d_in[24];
    const float* ncb2  = (const float*)d_in[25];
    const float* clW1  = (const float*)d_in[26];
    const float* clb1  = (const float*)d_in[27];
    const float* clW2  = (const float*)d_in[28];
    const float* clb2  = (const float*)d_in[29];

    char* w = (char*)d_ws;
    size_t used = 0;
    auto alloc = [&](size_t b) {
        char* p = w + used; used += (b + 255) & ~(size_t)255; return p;
    };
    u16* nf0  = (u16*)alloc((size_t)NN * 64 * 2);
    u16* nfW  = (u16*)alloc((size_t)NN * 64 * 2);
    u16* ef0  = (u16*)alloc((size_t)EE * 64 * 2);   // PERMUTED (CSR position order)
    u16* efW  = (u16*)alloc((size_t)EE * 64 * 2);   // PERMUTED
    u16* pmW1 = (u16*)alloc(49152 * 2);   // mp edge MLP L1: K=384 N=128
    u16* pmW2 = (u16*)alloc(8192 * 2);    // mp edge MLP L2: K=128 N=64
    u16* pnW1 = (u16*)alloc(8192 * 2);    // node embed L1:  K=128 N=64
    u16* pnW2 = (u16*)alloc(4096 * 2);    // node embed L2:  K=64  N=64
    u16* peW1 = (u16*)alloc(2048 * 2);    // edge embed L1:  K=19->32 N=64
    u16* peW2 = (u16*)alloc(4096 * 2);    // edge embed L2:  K=64  N=64
    u16* pcW1 = (u16*)alloc(2048 * 2);    // edge head L1:   K=64  N=32
    int* cnt    = (int*)alloc((size_t)NN * 4);       // reused as `cur`
    int* starts = (int*)alloc((size_t)(NN + 1) * 4);
    int* eids   = (int*)alloc((size_t)EE * 4);
    int* psrc   = (int*)alloc((size_t)EE * 4);
    int* pdst   = (int*)alloc((size_t)EE * 4);
    if (used > ws_size) return;

    pack_frag<<<192, 256, 0, stream>>>(mpW1, pmW1, 384, 128);
    pack_frag<<<32, 256, 0, stream>>>(mpW2, pmW2, 128, 64);
    pack_frag<<<32, 256, 0, stream>>>(neW1, pnW1, 128, 64);
    pack_frag<<<16, 256, 0, stream>>>(neW2, pnW2, 64, 64);
    pack_frag<<<8, 256, 0, stream>>>(eeW1, peW1, 19, 64);
    pack_frag<<<16, 256, 0, stream>>>(eeW2, peW2, 64, 64);
    pack_frag<<<8, 256, 0, stream>>>(ecW1, pcW1, 64, 32);

    // CSR build first (embed_edge + edge loop consume the permutation)
    zero_cnt<<<(NN + 255) / 256, 256, 0, stream>>>(cnt);
    count_deg<<<EE / 256, 256, 0, stream>>>(eidx, cnt);
    scan_k<<<1, 1024, 0, stream>>>(cnt, starts);
    init_cur<<<(NN + 255) / 256, 256, 0, stream>>>(starts, cnt);
    scatter_e<<<EE / 256, 256, 0, stream>>>(eidx, cnt, eids);
    build_perm<<<EE / 256, 256, 0, stream>>>(eidx, eids, psrc, pdst);

    embed_mfma_node<<<(NN + 63) / 64, 256, 0, stream>>>(x, pnW1, neb1, pnW2, neb2, nf0);
    embed_mfma_edge<<<EE / 64, 256, 0, stream>>>(ea, eids, peW1, eeb1, peW2, eeb2, ef0);

    float* outE = (float*)d_out;
    float* outN = outE + EE;
    float* outC = outN + NN;

    const u16* nfc = nf0;
    const u16* efc = ef0;
    for (int s = 0; s < 6; ++s) {
        edge_mlp<<<EE / 64, 256, 0, stream>>>(psrc, pdst, nf0, nfc, ef0, efc,
                                              pmW1, pmW2, mpb1, mpb2, efW,
                                              eids, pcW1, ecb1, ecW2, ecb2, outE,
                                              (s == 3) ? 1 : 0);
        node_update<<<(NN + 15) / 16, 256, 0, stream>>>(efW, starts, mpnW, mpnb, nfW);
        efc = efW;
        nfc = nfW;
    }
    node_head<<<(NN + 255) / 256, 256, 0, stream>>>(nfc, ncW1, ncb1, ncW2, ncb2,
                                                    clW1, clb1, clW2, clb2, outN, outC);
    (void)in_sizes; (void)n_in; (void)out_size;
}

// Round 9
// 1233.619 us; speedup vs baseline: 1.4970x; 1.1320x over previous
//
#include <hip/hip_runtime.h>

#define NN 50000
#define EE 800000

typedef unsigned short u16;
typedef __attribute__((ext_vector_type(8))) short bf16x8;
typedef __attribute__((ext_vector_type(4))) float f32x4;

#define MFMA16(a, b, c) __builtin_amdgcn_mfma_f32_16x16x32_bf16(a, b, c, 0, 0, 0)

__device__ __forceinline__ float bf2f(u16 v) {
    union { unsigned u; float f; } x; x.u = ((unsigned)v) << 16; return x.f;
}
__device__ __forceinline__ u16 f2bf(float f) {
    union { float f; unsigned u; } x; x.f = f;
    unsigned r = x.u + 0x7FFFu + ((x.u >> 16) & 1u);
    return (u16)(r >> 16);
}
__device__ __forceinline__ void gl_lds16(const u16* g, u16* l) {
    __builtin_amdgcn_global_load_lds((const __attribute__((address_space(1))) void*)g,
                                     (__attribute__((address_space(3))) void*)l, 16, 0, 0);
}

// ---------------- generic weight packing (fragment-major bf16) ----------------
// dst[kk][nf][lane][t]: k = kk*32 + (lane>>4)*8 + t (zero-padded past K), n = nf*16 + (lane&15)
__global__ void pack_frag(const float* __restrict__ W, u16* __restrict__ dst, int K, int N) {
    int i = blockIdx.x * 256 + threadIdx.x;
    int nfc = N / 16, kkc = (K + 31) / 32;
    int total = kkc * nfc * 512;
    if (i >= total) return;
    int t = i & 7, lane = (i >> 3) & 63;
    int rest = i >> 9;
    int nf = rest % nfc, kk = rest / nfc;
    int k = kk * 32 + (lane >> 4) * 8 + t, n = nf * 16 + (lane & 15);
    dst[i] = (k < K) ? f2bf(W[k * N + n]) : (u16)0;
}

// ---------------- MFMA node embedding ----------------
__global__ __launch_bounds__(256) void embed_mfma_node(
    const float* __restrict__ x, const u16* __restrict__ pW1, const float* __restrict__ b1,
    const u16* __restrict__ pW2, const float* __restrict__ b2, u16* __restrict__ out)
{
    __shared__ alignas(16) u16 A[64 * 136];
    __shared__ alignas(16) u16 Hs[64 * 72];
    int tid = threadIdx.x;
    size_t row0 = (size_t)blockIdx.x * 64;
    #pragma unroll
    for (int it = 0; it < 8; ++it) {
        int u = it * 256 + tid;
        int row = u >> 5, seg = u & 31;
        float4 v = (row0 + row < NN) ? *(const float4*)(x + (row0 + row) * 128 + seg * 4)
                                     : make_float4(0.f, 0.f, 0.f, 0.f);
        ushort4 o; o.x = f2bf(v.x); o.y = f2bf(v.y); o.z = f2bf(v.z); o.w = f2bf(v.w);
        *(ushort4*)(A + row * 136 + seg * 4) = o;
    }
    __syncthreads();
    int wave = tid >> 6, lane = tid & 63, l15 = lane & 15, l4 = lane >> 4;
    int col = wave * 16 + l15;
    f32x4 acc[4] = {};
    #pragma unroll
    for (int kk = 0; kk < 4; ++kk) {
        bf16x8 b = *(const bf16x8*)(pW1 + (size_t)((kk * 4 + wave) * 64 + lane) * 8);
        #pragma unroll
        for (int mi = 0; mi < 4; ++mi) {
            bf16x8 a = *(const bf16x8*)(A + (mi * 16 + l15) * 136 + kk * 32 + l4 * 8);
            acc[mi] = MFMA16(a, b, acc[mi]);
        }
    }
    float bias = b1[col];
    #pragma unroll
    for (int mi = 0; mi < 4; ++mi)
        #pragma unroll
        for (int r = 0; r < 4; ++r) {
            float v = acc[mi][r] + bias;
            Hs[(mi * 16 + l4 * 4 + r) * 72 + col] = f2bf(v > 0.f ? v : 0.f);
        }
    __syncthreads();
    f32x4 acc2[4] = {};
    #pragma unroll
    for (int kk = 0; kk < 2; ++kk) {
        bf16x8 b = *(const bf16x8*)(pW2 + (size_t)((kk * 4 + wave) * 64 + lane) * 8);
        #pragma unroll
        for (int mi = 0; mi < 4; ++mi) {
            bf16x8 a = *(const bf16x8*)(Hs + (mi * 16 + l15) * 72 + kk * 32 + l4 * 8);
            acc2[mi] = MFMA16(a, b, acc2[mi]);
        }
    }
    float bias2 = b2[col];
    __syncthreads();
    #pragma unroll
    for (int mi = 0; mi < 4; ++mi)
        #pragma unroll
        for (int r = 0; r < 4; ++r)
            Hs[(mi * 16 + l4 * 4 + r) * 72 + col] = f2bf(acc2[mi][r] + bias2);
    __syncthreads();
    #pragma unroll
    for (int it = 0; it < 4; ++it) {
        int u = it * 256 + tid;
        int row = u >> 4, c4 = (u & 15) * 4;
        if (row0 + row < NN) {
            ushort4 o = *(const ushort4*)(Hs + row * 72 + c4);
            *(ushort4*)(out + (row0 + row) * 64 + c4) = o;
        }
    }
}

// ---------------- MFMA edge embedding (gathers ea rows by eids -> writes PERMUTED ef0) ----------------
__global__ __launch_bounds__(256) void embed_mfma_edge(
    const float* __restrict__ ea, const int* __restrict__ eids,
    const u16* __restrict__ pW1, const float* __restrict__ b1,
    const u16* __restrict__ pW2, const float* __restrict__ b2, u16* __restrict__ out)
{
    __shared__ alignas(16) u16 A[64 * 40];
    __shared__ alignas(16) u16 Hs[64 * 72];
    __shared__ int eid_s[64];
    int tid = threadIdx.x;
    size_t row0 = (size_t)blockIdx.x * 64;
    if (tid < 64) eid_s[tid] = eids[row0 + tid];
    __syncthreads();
    #pragma unroll
    for (int it = 0; it < 8; ++it) {
        int u = it * 256 + tid;
        int row = u >> 5, k = u & 31;
        float v = (k < 19) ? ea[(size_t)eid_s[row] * 19 + k] : 0.f;
        A[row * 40 + k] = f2bf(v);
    }
    __syncthreads();
    int wave = tid >> 6, lane = tid & 63, l15 = lane & 15, l4 = lane >> 4;
    int col = wave * 16 + l15;
    f32x4 acc[4] = {};
    {
        bf16x8 b = *(const bf16x8*)(pW1 + (size_t)(wave * 64 + lane) * 8);
        #pragma unroll
        for (int mi = 0; mi < 4; ++mi) {
            bf16x8 a = *(const bf16x8*)(A + (mi * 16 + l15) * 40 + l4 * 8);
            acc[mi] = MFMA16(a, b, acc[mi]);
        }
    }
    float bias = b1[col];
    #pragma unroll
    for (int mi = 0; mi < 4; ++mi)
        #pragma unroll
        for (int r = 0; r < 4; ++r) {
            float v = acc[mi][r] + bias;
            Hs[(mi * 16 + l4 * 4 + r) * 72 + col] = f2bf(v > 0.f ? v : 0.f);
        }
    __syncthreads();
    f32x4 acc2[4] = {};
    #pragma unroll
    for (int kk = 0; kk < 2; ++kk) {
        bf16x8 b = *(const bf16x8*)(pW2 + (size_t)((kk * 4 + wave) * 64 + lane) * 8);
        #pragma unroll
        for (int mi = 0; mi < 4; ++mi) {
            bf16x8 a = *(const bf16x8*)(Hs + (mi * 16 + l15) * 72 + kk * 32 + l4 * 8);
            acc2[mi] = MFMA16(a, b, acc2[mi]);
        }
    }
    float bias2 = b2[col];
    __syncthreads();
    #pragma unroll
    for (int mi = 0; mi < 4; ++mi)
        #pragma unroll
        for (int r = 0; r < 4; ++r)
            Hs[(mi * 16 + l4 * 4 + r) * 72 + col] = f2bf(acc2[mi][r] + bias2);
    __syncthreads();
    #pragma unroll
    for (int it = 0; it < 4; ++it) {
        int u = it * 256 + tid;
        int row = u >> 4, c4 = (u & 15) * 4;
        ushort4 o = *(const ushort4*)(Hs + row * 72 + c4);
        *(ushort4*)(out + (row0 + row) * 64 + c4) = o;
    }
}

// ---------------- CSR build ----------------
__global__ void zero_cnt(int* __restrict__ cnt) {
    int i = blockIdx.x * 256 + threadIdx.x;
    if (i < NN) cnt[i] = 0;
}
__global__ void count_deg(const int* __restrict__ eidx, int* __restrict__ cnt) {
    int e = blockIdx.x * 256 + threadIdx.x;
    if (e < EE) atomicAdd(&cnt[eidx[EE + e]], 1);
}
__global__ void scan_k(const int* __restrict__ cnt, int* __restrict__ starts) {
    __shared__ int part[1024];
    int t = threadIdx.x;
    const int chunk = (NN + 1023) / 1024;
    int lo = t * chunk, hi = lo + chunk; if (hi > NN) hi = NN;
    if (lo > NN) lo = NN;
    int s = 0;
    for (int i = lo; i < hi; ++i) s += cnt[i];
    part[t] = s;
    __syncthreads();
    for (int off = 1; off < 1024; off <<= 1) {
        int v = part[t];
        int add = (t >= off) ? part[t - off] : 0;
        __syncthreads();
        part[t] = v + add;
        __syncthreads();
    }
    int run = (t == 0) ? 0 : part[t - 1];
    for (int i = lo; i < hi; ++i) { starts[i] = run; run += cnt[i]; }
    if (t == 1023) starts[NN] = EE;
}
__global__ void init_cur(const int* __restrict__ starts, int* __restrict__ cur) {
    int i = blockIdx.x * 256 + threadIdx.x;
    if (i < NN) cur[i] = starts[i];
}
__global__ void scatter_e(const int* __restrict__ eidx, int* __restrict__ cur,
                          int* __restrict__ eids) {
    int e = blockIdx.x * 256 + threadIdx.x;
    if (e < EE) {
        int pos = atomicAdd(&cur[eidx[EE + e]], 1);
        eids[pos] = e;
    }
}
__global__ void build_perm(const int* __restrict__ eidx, const int* __restrict__ eids,
                           int* __restrict__ psrc, int* __restrict__ pdst) {
    int j = blockIdx.x * 256 + threadIdx.x;
    if (j < EE) {
        int e = eids[j];
        psrc[j] = eidx[e];
        pdst[j] = eidx[EE + e];
    }
}

// ---------------- fused edge MLP v11: exact v6 schedule + fused edge head ----------------
// Byte-identical schedule/numerics to the verified v6 kernel (6 x 8KB buffers, 48KB LDS,
// 3 blocks/CU, pinned W1 fragments, vmcnt ladder 10,8,6,4,2,0, Hid overlays buf0-1,
// EnF overlays buf2-3). Added only: at s==3 the edge head is computed inline from EnF
// (A = f2bf(EnF) == the stored efW bf16 values -> bit-identical to the standalone
// edge_head kernel) - deletes a 102MB-read dispatch.
__global__ __launch_bounds__(256, 3) void edge_mlp(
    const int* __restrict__ psrc, const int* __restrict__ pdst,
    const u16* __restrict__ nf0, const u16* __restrict__ nfc,
    const u16* __restrict__ ef0, const u16* __restrict__ efc,
    const u16* __restrict__ pW1, const u16* __restrict__ pW2,
    const float* __restrict__ eb1, const float* __restrict__ eb2,
    u16* __restrict__ efn,
    const int* __restrict__ eids, const u16* __restrict__ pcW1,
    const float* __restrict__ hb1, const float* __restrict__ hW2,
    const float* __restrict__ hb2, float* __restrict__ outE, int doHead)
{
    __shared__ alignas(16) u16 Chunk[6][64 * 64];   // 48KB
    const int tid = threadIdx.x;
    const int tile0 = blockIdx.x * 64;
    const int wave = tid >> 6, lane = tid & 63;
    const int l15 = lane & 15, l4 = lane >> 4;

    // per-lane DMA geometry: 8 lanes cover one row (8 x 16B units); lane owns rows r0,r1
    const int r0 = wave * 16 + (lane >> 3);
    const int r1 = r0 + 8;
    const int u_ = lane & 7;
    const int su0 = u_ ^ (r0 & 7);        // pre-swizzled source unit (XOR involution)
    const int su1 = u_ ^ (r1 & 7);
    const int is0 = psrc[tile0 + r0] * 64;
    const int is1 = psrc[tile0 + r1] * 64;
    const int id0 = pdst[tile0 + r0] * 64;
    const int id1 = pdst[tile0 + r1] * 64;

    // ---- preload + pin ALL W1 fragments (24 x 4 VGPR = 96 VGPR) ----
    bf16x8 bw[24];
    #pragma unroll
    for (int kk = 0; kk < 12; ++kk) {
        bw[kk * 2 + 0] = *(const bf16x8*)(pW1 + (size_t)((kk * 8 + wave * 2 + 0) * 64 + lane) * 8);
        bw[kk * 2 + 1] = *(const bf16x8*)(pW1 + (size_t)((kk * 8 + wave * 2 + 1) * 64 + lane) * 8);
    }
    #pragma unroll
    for (int i = 0; i < 24; ++i) asm volatile("" : "+v"(bw[i]));
    __builtin_amdgcn_sched_barrier(0);

    // ---- issue all 6 chunks (12 DMA loads/lane in flight) ----
    #pragma unroll
    for (int c = 0; c < 6; ++c) {
        const u16 *b0, *b1;
        if (c == 0)      { b0 = nf0 + is0; b1 = nf0 + is1; }
        else if (c == 1) { b0 = nfc + is0; b1 = nfc + is1; }
        else if (c == 2) { b0 = nf0 + id0; b1 = nf0 + id1; }
        else if (c == 3) { b0 = nfc + id0; b1 = nfc + id1; }
        else if (c == 4) { b0 = ef0 + (size_t)(tile0 + r0) * 64; b1 = ef0 + (size_t)(tile0 + r1) * 64; }
        else             { b0 = efc + (size_t)(tile0 + r0) * 64; b1 = efc + (size_t)(tile0 + r1) * 64; }
        u16* l0 = (u16*)Chunk + c * 4096 + wave * 1024;   // + lane*16B by HW; row r1 at +512
        gl_lds16(b0 + su0 * 8, l0);
        gl_lds16(b1 + su1 * 8, l0 + 512);
    }
    __builtin_amdgcn_sched_barrier(0);

    // ---- GEMM1: [64 x 384] @ [384 x 128], counted-vmcnt ladder, 1 barrier/chunk ----
    f32x4 acc[4][2] = {};
    #pragma unroll
    for (int c = 0; c < 6; ++c) {
        if (c == 0)      asm volatile("s_waitcnt vmcnt(10)" ::: "memory");
        else if (c == 1) asm volatile("s_waitcnt vmcnt(8)" ::: "memory");
        else if (c == 2) asm volatile("s_waitcnt vmcnt(6)" ::: "memory");
        else if (c == 3) asm volatile("s_waitcnt vmcnt(4)" ::: "memory");
        else if (c == 4) asm volatile("s_waitcnt vmcnt(2)" ::: "memory");
        else             asm volatile("s_waitcnt vmcnt(0)" ::: "memory");
        __builtin_amdgcn_s_barrier();
        __builtin_amdgcn_sched_barrier(0);
        const char* Cb = (const char*)Chunk + c * 8192;
        #pragma unroll
        for (int kkl = 0; kkl < 2; ++kkl) {
            const int kk = c * 2 + kkl;
            #pragma unroll
            for (int mi = 0; mi < 4; ++mi) {
                int row = mi * 16 + l15;
                bf16x8 a = *(const bf16x8*)(Cb + row * 128 + ((kkl * 64 + l4 * 16) ^ ((row & 7) << 4)));
                acc[mi][0] = MFMA16(a, bw[kk * 2 + 0], acc[mi][0]);
                acc[mi][1] = MFMA16(a, bw[kk * 2 + 1], acc[mi][1]);
            }
        }
        // no trailing barrier: buffers are never overwritten during GEMM1
    }

    // hidden = relu(acc + b1) -> HidB (overlays Chunk[0..1], swizzled bf16)
    char* HidB = (char*)Chunk;
    #pragma unroll
    for (int nj = 0; nj < 2; ++nj) {
        int col = wave * 32 + nj * 16 + l15;
        float bias = eb1[col];
        #pragma unroll
        for (int mi = 0; mi < 4; ++mi) {
            #pragma unroll
            for (int r = 0; r < 4; ++r) {
                int row = mi * 16 + l4 * 4 + r;
                float v = acc[mi][nj][r] + bias;
                v = v > 0.f ? v : 0.f;
                *(u16*)(HidB + row * 256 + ((col * 2) ^ ((row & 7) << 4))) = f2bf(v);
            }
        }
    }
    __syncthreads();

    // GEMM2: [64x128]@[128x64]; wave owns rows wave*16..+15
    f32x4 acc2[4] = {};
    const int m0 = wave * 16;
    #pragma unroll
    for (int kk = 0; kk < 4; ++kk) {
        int row = m0 + l15;
        bf16x8 a = *(const bf16x8*)(HidB + row * 256 + ((kk * 64 + l4 * 16) ^ ((row & 7) << 4)));
        #pragma unroll
        for (int nf = 0; nf < 4; ++nf) {
            bf16x8 b = *(const bf16x8*)(pW2 + (size_t)((kk * 4 + nf) * 64 + lane) * 8);
            acc2[nf] = MFMA16(a, b, acc2[nf]);
        }
    }

    // e_new staging (f32 [64][64] overlays Chunk[2..3]), then coalesced bf16 store
    float* EnF = (float*)((char*)Chunk + 16384);
    #pragma unroll
    for (int nf = 0; nf < 4; ++nf) {
        int col = nf * 16 + l15;
        float bias = eb2[col];
        #pragma unroll
        for (int r = 0; r < 4; ++r) {
            int row = m0 + l4 * 4 + r;
            EnF[row * 64 + col] = acc2[nf][r] + bias;
        }
    }
    __syncthreads();
    #pragma unroll
    for (int rep = 0; rep < 4; ++rep) {
        int u = rep * 256 + tid;
        int el = u >> 4, d0 = (u & 15) * 4;
        const float* s = EnF + el * 64 + d0;
        ushort4 o;
        o.x = f2bf(s[0]); o.y = f2bf(s[1]); o.z = f2bf(s[2]); o.w = f2bf(s[3]);
        *(ushort4*)(efn + (size_t)(tile0 + el) * 64 + d0) = o;
    }

    // ---- fused edge head (s==3 only): A = f2bf(EnF), bit-identical to edge_head kernel ----
    if (doHead) {
        f32x4 hacc[2] = {};
        #pragma unroll
        for (int kk = 0; kk < 2; ++kk) {
            const float* s = EnF + (m0 + l15) * 64 + kk * 32 + l4 * 8;
            bf16x8 a;
            #pragma unroll
            for (int j = 0; j < 8; ++j) a[j] = (short)f2bf(s[j]);
            #pragma unroll
            for (int nf = 0; nf < 2; ++nf) {
                bf16x8 b = *(const bf16x8*)(pcW1 + (size_t)((kk * 2 + nf) * 64 + lane) * 8);
                hacc[nf] = MFMA16(a, b, hacc[nf]);
            }
        }
        float bias2 = hb2[0];
        #pragma unroll
        for (int r = 0; r < 4; ++r) {
            float p = 0.f;
            #pragma unroll
            for (int nf = 0; nf < 2; ++nf) {
                int col = nf * 16 + l15;
                float h = hacc[nf][r] + hb1[col];
                p += (h > 0.f ? h : 0.f) * hW2[col];
            }
            p += __shfl_xor(p, 1); p += __shfl_xor(p, 2);
            p += __shfl_xor(p, 4); p += __shfl_xor(p, 8);
            if (l15 == 0) outE[eids[tile0 + m0 + l4 * 4 + r]] = p + bias2;
        }
    }
}

// ---------------- node update: contiguous segmented sum (edges in CSR order) ----------------
// 16 nodes/block, one node per 16-lane group; rows starts[n]..starts[n+1] are ADJACENT in enewp.
__global__ __launch_bounds__(256) void node_update(
    const u16* __restrict__ enewp,
    const int* __restrict__ starts,
    const float* __restrict__ Wn, const float* __restrict__ bn,
    u16* __restrict__ nfn)
{
    __shared__ float Wns[64 * 64];
    int tid = threadIdx.x;
    for (int i = tid; i < 4096; i += 256) Wns[i] = Wn[i];
    __syncthreads();
    const int l = tid & 63;
    const int q = l & 15;
    const int base = l & 48;
    const int n = blockIdx.x * 16 + (tid >> 4);
    if (n >= NN) return;
    const int s0 = starts[n], s1 = starts[n + 1];
    const int cnt = s1 - s0;
    const u16* p = enewp + (size_t)s0 * 64 + q * 4;
    float a0 = 0.f, a1 = 0.f, a2 = 0.f, a3 = 0.f;
    int i = 0;
    for (; i + 4 <= cnt; i += 4) {
        ushort4 v0 = *(const ushort4*)(p + (i + 0) * 64);
        ushort4 v1 = *(const ushort4*)(p + (i + 1) * 64);
        ushort4 v2 = *(const ushort4*)(p + (i + 2) * 64);
        ushort4 v3 = *(const ushort4*)(p + (i + 3) * 64);
        a0 += bf2f(v0.x) + bf2f(v1.x) + bf2f(v2.x) + bf2f(v3.x);
        a1 += bf2f(v0.y) + bf2f(v1.y) + bf2f(v2.y) + bf2f(v3.y);
        a2 += bf2f(v0.z) + bf2f(v1.z) + bf2f(v2.z) + bf2f(v3.z);
        a3 += bf2f(v0.w) + bf2f(v1.w) + bf2f(v2.w) + bf2f(v3.w);
    }
    for (; i < cnt; ++i) {
        ushort4 v0 = *(const ushort4*)(p + i * 64);
        a0 += bf2f(v0.x); a1 += bf2f(v0.y); a2 += bf2f(v0.z); a3 += bf2f(v0.w);
    }
    const float4 bb = *(const float4*)(bn + q * 4);
    float o0 = bb.x, o1 = bb.y, o2 = bb.z, o3 = bb.w;
    #pragma unroll
    for (int hq = 0; hq < 16; ++hq) {
        int src = base | hq;
        float b0 = __shfl(a0, src), b1 = __shfl(a1, src);
        float b2 = __shfl(a2, src), b3 = __shfl(a3, src);
        const float4 w0 = *(const float4*)(Wns + (hq * 4 + 0) * 64 + q * 4);
        const float4 w1 = *(const float4*)(Wns + (hq * 4 + 1) * 64 + q * 4);
        const float4 w2 = *(const float4*)(Wns + (hq * 4 + 2) * 64 + q * 4);
        const float4 w3 = *(const float4*)(Wns + (hq * 4 + 3) * 64 + q * 4);
        o0 += b0 * w0.x + b1 * w1.x + b2 * w2.x + b3 * w3.x;
        o1 += b0 * w0.y + b1 * w1.y + b2 * w2.y + b3 * w3.y;
        o2 += b0 * w0.z + b1 * w1.z + b2 * w2.z + b3 * w3.z;
        o3 += b0 * w0.w + b1 * w1.w + b2 * w2.w + b3 * w3.w;
    }
    ushort4 o;
    o.x = f2bf(o0 > 0.f ? o0 : 0.f);
    o.y = f2bf(o1 > 0.f ? o1 : 0.f);
    o.z = f2bf(o2 > 0.f ? o2 : 0.f);
    o.w = f2bf(o3 > 0.f ? o3 : 0.f);
    *(ushort4*)(nfn + (size_t)n * 64 + q * 4) = o;
}

// ---------------- node head ----------------
__global__ void node_head(const u16* __restrict__ nf,
                          const float* __restrict__ ncW1, const float* __restrict__ ncb1,
                          const float* __restrict__ ncW2, const float* __restrict__ ncb2,
                          const float* __restrict__ clW1, const float* __restrict__ clb1,
                          const float* __restrict__ clW2, const float* __restrict__ clb2,
                          float* __restrict__ outN, float* __restrict__ outC) {
    __shared__ float sNW1[2048], sCW1[2048], sCW2[32 * 17];
    __shared__ float sNb1[32], sCb1[32], sNW2[32], sCb2[17];
    int tid = threadIdx.x;
    for (int i = tid; i < 2048; i += 256) { sNW1[i] = ncW1[i]; sCW1[i] = clW1[i]; }
    for (int i = tid; i < 544; i += 256) sCW2[i] = clW2[i];
    if (tid < 32) { sNb1[tid] = ncb1[tid]; sCb1[tid] = clb1[tid]; sNW2[tid] = ncW2[tid]; }
    if (tid < 17) sCb2[tid] = clb2[tid];
    __syncthreads();
    int n = blockIdx.x * 256 + tid;
    if (n >= NN) return;
    const u16* r = nf + (size_t)n * 64;
    float v[64];
    for (int k4 = 0; k4 < 16; ++k4) {
        ushort4 q = *(const ushort4*)(r + k4 * 4);
        v[k4 * 4 + 0] = bf2f(q.x); v[k4 * 4 + 1] = bf2f(q.y);
        v[k4 * 4 + 2] = bf2f(q.z); v[k4 * 4 + 3] = bf2f(q.w);
    }
    float h[32];
    #pragma unroll
    for (int j = 0; j < 32; ++j) h[j] = sNb1[j];
    for (int k = 0; k < 64; ++k) {
        float vk = v[k];
        #pragma unroll
        for (int j = 0; j < 32; ++j) h[j] += vk * sNW1[k * 32 + j];
    }
    float o = ncb2[0];
    #pragma unroll
    for (int j = 0; j < 32; ++j) o += (h[j] > 0.f ? h[j] : 0.f) * sNW2[j];
    outN[n] = o;
    #pragma unroll
    for (int j = 0; j < 32; ++j) h[j] = sCb1[j];
    for (int k = 0; k < 64; ++k) {
        float vk = v[k];
        #pragma unroll
        for (int j = 0; j < 32; ++j) h[j] += vk * sCW1[k * 32 + j];
    }
    float oc[17];
    #pragma unroll
    for (int c = 0; c < 17; ++c) oc[c] = sCb2[c];
    #pragma unroll
    for (int j = 0; j < 32; ++j) {
        float hr = h[j] > 0.f ? h[j] : 0.f;
        #pragma unroll
        for (int c = 0; c < 17; ++c) oc[c] += hr * sCW2[j * 17 + c];
    }
    #pragma unroll
    for (int c = 0; c < 17; ++c) outC[(size_t)n * 17 + c] = oc[c];
}

// ---------------- launch ----------------
extern "C" void kernel_launch(void* const* d_in, const int* in_sizes, int n_in,
                              void* d_out, int out_size, void* d_ws, size_t ws_size,
                              hipStream_t stream) {
    const float* x     = (const float*)d_in[0];
    const float* ea    = (const float*)d_in[1];
    const int*   eidx  = (const int*)d_in[2];
    const float* neW1  = (const float*)d_in[4];
    const float* neb1  = (const float*)d_in[5];
    const float* neW2  = (const float*)d_in[6];
    const float* neb2  = (const float*)d_in[7];
    const float* eeW1  = (const float*)d_in[8];
    const float* eeb1  = (const float*)d_in[9];
    const float* eeW2  = (const float*)d_in[10];
    const float* eeb2  = (const float*)d_in[11];
    const float* mpW1  = (const float*)d_in[12];
    const float* mpb1  = (const float*)d_in[13];
    const float* mpW2  = (const float*)d_in[14];
    const float* mpb2  = (const float*)d_in[15];
    const float* mpnW  = (const float*)d_in[16];
    const float* mpnb  = (const float*)d_in[17];
    const float* ecW1  = (const float*)d_in[18];
    const float* ecb1  = (const float*)d_in[19];
    const float* ecW2  = (const float*)d_in[20];
    const float* ecb2  = (const float*)d_in[21];
    const float* ncW1  = (const float*)d_in[22];
    const float* ncb1  = (const float*)d_in[23];
    const float* ncW2  = (const float*)d_in[24];
    const float* ncb2  = (const float*)d_in[25];
    const float* clW1  = (const float*)d_in[26];
    const float* clb1  = (const float*)d_in[27];
    const float* clW2  = (const float*)d_in[28];
    const float* clb2  = (const float*)d_in[29];

    char* w = (char*)d_ws;
    size_t used = 0;
    auto alloc = [&](size_t b) {
        char* p = w + used; used += (b + 255) & ~(size_t)255; return p;
    };
    u16* nf0  = (u16*)alloc((size_t)NN * 64 * 2);
    u16* nfW  = (u16*)alloc((size_t)NN * 64 * 2);
    u16* ef0  = (u16*)alloc((size_t)EE * 64 * 2);   // PERMUTED (CSR position order)
    u16* efW  = (u16*)alloc((size_t)EE * 64 * 2);   // PERMUTED
    u16* pmW1 = (u16*)alloc(49152 * 2);   // mp edge MLP L1: K=384 N=128
    u16* pmW2 = (u16*)alloc(8192 * 2);    // mp edge MLP L2: K=128 N=64
    u16* pnW1 = (u16*)alloc(8192 * 2);    // node embed L1:  K=128 N=64
    u16* pnW2 = (u16*)alloc(4096 * 2);    // node embed L2:  K=64  N=64
    u16* peW1 = (u16*)alloc(2048 * 2);    // edge embed L1:  K=19->32 N=64
    u16* peW2 = (u16*)alloc(4096 * 2);    // edge embed L2:  K=64  N=64
    u16* pcW1 = (u16*)alloc(2048 * 2);    // edge head L1:   K=64  N=32
    int* cnt    = (int*)alloc((size_t)NN * 4);       // reused as `cur`
    int* starts = (int*)alloc((size_t)(NN + 1) * 4);
    int* eids   = (int*)alloc((size_t)EE * 4);
    int* psrc   = (int*)alloc((size_t)EE * 4);
    int* pdst   = (int*)alloc((size_t)EE * 4);
    if (used > ws_size) return;

    pack_frag<<<192, 256, 0, stream>>>(mpW1, pmW1, 384, 128);
    pack_frag<<<32, 256, 0, stream>>>(mpW2, pmW2, 128, 64);
    pack_frag<<<32, 256, 0, stream>>>(neW1, pnW1, 128, 64);
    pack_frag<<<16, 256, 0, stream>>>(neW2, pnW2, 64, 64);
    pack_frag<<<8, 256, 0, stream>>>(eeW1, peW1, 19, 64);
    pack_frag<<<16, 256, 0, stream>>>(eeW2, peW2, 64, 64);
    pack_frag<<<8, 256, 0, stream>>>(ecW1, pcW1, 64, 32);

    // CSR build first (embed_edge + edge loop consume the permutation)
    zero_cnt<<<(NN + 255) / 256, 256, 0, stream>>>(cnt);
    count_deg<<<EE / 256, 256, 0, stream>>>(eidx, cnt);
    scan_k<<<1, 1024, 0, stream>>>(cnt, starts);
    init_cur<<<(NN + 255) / 256, 256, 0, stream>>>(starts, cnt);
    scatter_e<<<EE / 256, 256, 0, stream>>>(eidx, cnt, eids);
    build_perm<<<EE / 256, 256, 0, stream>>>(eidx, eids, psrc, pdst);

    embed_mfma_node<<<(NN + 63) / 64, 256, 0, stream>>>(x, pnW1, neb1, pnW2, neb2, nf0);
    embed_mfma_edge<<<EE / 64, 256, 0, stream>>>(ea, eids, peW1, eeb1, peW2, eeb2, ef0);

    float* outE = (float*)d_out;
    float* outN = outE + EE;
    float* outC = outN + NN;

    const u16* nfc = nf0;
    const u16* efc = ef0;
    for (int s = 0; s < 6; ++s) {
        edge_mlp<<<EE / 64, 256, 0, stream>>>(psrc, pdst, nf0, nfc, ef0, efc,
                                              pmW1, pmW2, mpb1, mpb2, efW,
                                              eids, pcW1, ecb1, ecW2, ecb2, outE,
                                              (s == 3) ? 1 : 0);
        node_update<<<(NN + 15) / 16, 256, 0, stream>>>(efW, starts, mpnW, mpnb, nfW);
        efc = efW;
        nfc = nfW;
    }
    node_head<<<(NN + 255) / 256, 256, 0, stream>>>(nfc, ncW1, ncb1, ncW2, ncb2,
                                                    clW1, clb1, clW2, clb2, outN, outC);
    (void)in_sizes; (void)n_in; (void)out_size;
}